// Round 1
// baseline (259.946 us; speedup 1.0000x reference)
//
#include <hip/hip_runtime.h>

#define N_GROUPS  8
#define PDIM      8
#define MAX_TABLE 32768
#define BATCH     524288
#define QUART     (BATCH / 4)

// Native clang vector types — required by __builtin_nontemporal_load/store.
typedef int   vi4 __attribute__((ext_vector_type(4)));
typedef float vf4 __attribute__((ext_vector_type(4)));

#define TT_FLOATS (65280 * 8)   // compact table: 522240 floats = 2.04 MiB

// ---------------------------------------------------------------------------
// Pass 1: (a) transpose + compact group_tables (8,8,32768) -> tt (65280,8):
// group g only uses addr < 2^(8+g); row g starts at entry 256*(2^g - 1).
// (b) block 0 additionally bit-packs carry_tables (7,256) int32 0/1 into
// 28 uint64s (224 B) so the mapper's carry lookup is a 4-line L1-resident
// table instead of ~30 scattered line-requests per wave.
// ---------------------------------------------------------------------------
__global__ __launch_bounds__(256) void transpose_tables(
    const float* __restrict__ gt,   // (8, 8, 32768)
    const int*   __restrict__ ct,   // (7, 256) 0/1 int32
    float*       __restrict__ tt,   // compact (65280, 8)
    unsigned long long* __restrict__ ctpack)  // 28 x u64
{
    if (blockIdx.x == 0 && threadIdx.x < 28) {
        const int g = threadIdx.x >> 2, w = threadIdx.x & 3;
        const int* src = ct + g * 256 + w * 64;
        unsigned long long m = 0;
        #pragma unroll 8
        for (int b = 0; b < 64; ++b)
            m |= (unsigned long long)(src[b] & 1) << b;
        ctpack[threadIdx.x] = m;
    }

    const int i  = blockIdx.x * blockDim.x + threadIdx.x;   // 0 .. 524287
    const int a4 = i & (MAX_TABLE / 4 - 1);
    const int gp = i >> 13;
    const int p  = gp & 7;
    const int g  = gp >> 3;
    const int a  = a4 * 4;
    if (a >= (256 << g)) return;                            // beyond live prefix

    const vf4 v = reinterpret_cast<const vf4*>(gt)[i];      // coalesced
    const int ro = 256 * ((1 << g) - 1);                    // compact row offset
    float* base = tt + (size_t)(ro + a) * PDIM + p;
    base[0 * PDIM] = v.x;
    base[1 * PDIM] = v.y;
    base[2 * PDIM] = v.z;
    base[3 * PDIM] = v.w;
}

// ---------------------------------------------------------------------------
// Pass 2: one thread per (element, group), FOUR elements per thread
// (e0 + k*QUART, k=0..3) for ILP. Lane layout: lane = eq*8 + g (eq = element
// slot within the wave, g = group). Each thread:
//   - loads its group's 8 bit-ints (32 B, nontemporal; no twin duplication),
//   - computes gaddr + carry from the 224 B L1-resident packed carry table,
//   - one ballot: byte eq of the mask directly holds carries c_0..c_6 of
//     element eq (bit j = c_j) -- no even-bit compress needed,
//   - loads the full 8-float compact-table row (2 x 16 B, same 64 B line),
//   - stores 32 B of the output row.
// Per-wave, the two load/store instructions of each pair jointly cover full
// contiguous 2 KB spans (lines merge in L1/L2), so HBM traffic is unchanged
// while instruction count and bits-side request traffic halve vs the
// (element, group, half)-per-thread layout.
// ---------------------------------------------------------------------------
__global__ __launch_bounds__(256) void comp_mapper_kernel(
    const int*   __restrict__ bits,   // (BATCH, 64) 0/1 int32
    const float* __restrict__ tab,    // compact transposed table (L2-resident)
    const unsigned long long* __restrict__ ctpack,  // 28 x u64 (L1-resident)
    float*       __restrict__ out)    // (BATCH, 64) fp32
{
    const int tid = blockIdx.x * blockDim.x + threadIdx.x;  // 0 .. QUART*8-1
    const int g   = tid & 7;
    const int eq  = (tid >> 3) & 7;         // element slot within wave
    const int e0  = (tid >> 6) * 8 + eq;    // element index (k=0), < QUART
    const int ro  = 256 * ((1 << g) - 1);   // compact row offset for group g

    int addrv[4];

    #pragma unroll
    for (int k = 0; k < 4; ++k) {
        const vi4* bp = reinterpret_cast<const vi4*>(bits)
                      + (size_t)(e0 + k * QUART) * 16 + g * 2;
        vi4 x = __builtin_nontemporal_load(bp);
        vi4 y = __builtin_nontemporal_load(bp + 1);

        // gaddr: bit j (j=0 first) has weight 2^(7-j)
        int ga = (x.x << 7) | (x.y << 6) | (x.z << 5) | (x.w << 4)
               | (y.x << 3) | (y.y << 2) | (y.z << 1) |  y.w;

        // carry from bit-packed table (groups 0..6; g==7 contributes 0)
        int c = 0;
        if (g < 7) c = (int)((ctpack[g * 4 + (ga >> 6)] >> (ga & 63)) & 1ull);

        // one ballot: byte eq holds this element's carries, bit j = c_j
        unsigned long long m = __ballot(c);
        unsigned f = (unsigned)((m >> (eq * 8)) & 0xFFull);
        // v = sum_{j<g} c_j * 2^(g-1-j) = brev8(f) >> (8-g)   (g=0 -> 0)
        unsigned v = (__brev(f) >> 24) >> (8 - g);

        addrv[k] = (ga << g) | (int)v;
    }

    const vf4* tt4 = reinterpret_cast<const vf4*>(tab);
    vf4* op = reinterpret_cast<vf4*>(out);
    #pragma unroll
    for (int k = 0; k < 4; ++k) {
        const size_t r2 = (size_t)(ro + addrv[k]) * 2;
        vf4 o0 = tt4[r2];           // 64 B line fetch (random, L2-resident)
        vf4 o1 = tt4[r2 + 1];       // same line -> L1 hit
        const size_t oi = (size_t)(e0 + k * QUART) * 16 + g * 2;
        __builtin_nontemporal_store(o0, op + oi);
        __builtin_nontemporal_store(o1, op + oi + 1);
    }
}

extern "C" void kernel_launch(void* const* d_in, const int* in_sizes, int n_in,
                              void* d_out, int out_size, void* d_ws, size_t ws_size,
                              hipStream_t stream) {
    const int*   bits = (const int*)  d_in[0];
    const float* gt   = (const float*)d_in[1];
    const int*   ct   = (const int*)  d_in[2];
    float*       out  = (float*)      d_out;

    const int block = 256;

    float* tt = (float*)d_ws;
    unsigned long long* ctpack =
        (unsigned long long*)((char*)d_ws + (size_t)TT_FLOATS * sizeof(float));

    const int t_threads = N_GROUPS * PDIM * MAX_TABLE / 4;   // 524288
    transpose_tables<<<t_threads / block, block, 0, stream>>>(gt, ct, tt, ctpack);

    const int m_threads = QUART * 8;                         // 1,048,576
    comp_mapper_kernel<<<m_threads / block, block, 0, stream>>>(bits, tt, ctpack, out);
}